// Round 2
// baseline (1561.423 us; speedup 1.0000x reference)
//
#include <hip/hip_runtime.h>
#include <hip/hip_bf16.h>

#define EPS       0.05f
#define N_ITERS   20
#define NR        8192      // N == M
#define DIM       64
#define LOG2E     1.4426950408889634f
#define LN2       0.6931471805599453f
#define S2        (2.0f * LOG2E / EPS)   // 57.7078...
#define EPSLN2    (EPS * LN2)

typedef __attribute__((ext_vector_type(8))) short short8;
typedef __attribute__((ext_vector_type(4))) float float4v;

__device__ __forceinline__ float wave_reduce_sum(float v) {
    #pragma unroll
    for (int m = 1; m < 64; m <<= 1) v += __shfl_xor(v, m, 64);
    return v;
}

// ---- setup: sums of a and b ------------------------------------------------
__global__ void sums_kernel(const float* __restrict__ a, const float* __restrict__ b,
                            float* __restrict__ sums) {
    __shared__ float red[32];
    int tid = threadIdx.x;
    float pa = 0.f, pb = 0.f;
    for (int i = tid; i < NR; i += blockDim.x) { pa += a[i]; pb += b[i]; }
    pa = wave_reduce_sum(pa);
    pb = wave_reduce_sum(pb);
    int wid = tid >> 6, ln = tid & 63;
    if (ln == 0) { red[wid] = pa; red[wid + 16] = pb; }
    __syncthreads();
    if (tid == 0) {
        float sa = 0.f, sb = 0.f;
        int nw = blockDim.x >> 6;
        for (int w = 0; w < nw; w++) { sa += red[w]; sb += red[w + 16]; }
        sums[0] = logf(sa); sums[1] = logf(sb); sums[2] = sa; sums[3] = sb;
    }
}

// ---- setup: bf16 copies, squared norms, log-weights, initial col bias ------
// one wave per row; lane k handles element k (DIM == 64)
__global__ void prep_kernel(const float* __restrict__ x, const float* __restrict__ y,
                            const float* __restrict__ a, const float* __restrict__ b,
                            const float* __restrict__ sums,
                            __hip_bfloat16* __restrict__ xb, __hip_bfloat16* __restrict__ yb,
                            float* __restrict__ x2, float* __restrict__ y2,
                            float* __restrict__ la2, float* __restrict__ lb2,
                            float* __restrict__ bias_c) {
    int gw = blockIdx.x * (blockDim.x >> 6) + (threadIdx.x >> 6);
    int ln = threadIdx.x & 63;
    bool isx = gw < NR;
    int row = isx ? gw : gw - NR;
    const float* src = isx ? x : y;
    float v = src[row * DIM + ln];
    float sq = wave_reduce_sum(v * v);
    (isx ? xb : yb)[row * DIM + ln] = __float2bfloat16(v);
    if (ln == 0) {
        if (isx) {
            x2[row] = sq;
            la2[row] = (logf(a[row]) - sums[0]) * LOG2E;
        } else {
            y2[row] = sq;
            float lw = (logf(b[row]) - sums[1]) * LOG2E;
            lb2[row] = lw;
            bias_c[row] = lw - sq * (LOG2E / EPS);   // g = 0 initially
        }
    }
}

// ---- one softmin sweep -----------------------------------------------------
// out_i = sq_row_i - eps*ln2 * LSE2_j( bias_in_j + S2 * <A_i, B_j> )
// bias_out_i = lw2_row_i - LSE2_i
// Block: 1024 thr = 16 waves; block covers 32 rows, each wave 512 cols.
// R2: software-pipelined B loads — next tile's b0/b1/cb issued before the
// epilogue of the current tile so L2 latency hides under the ~150-cyc LSE.
__global__ __launch_bounds__(1024) void pass_kernel(
        const __hip_bfloat16* __restrict__ matA,   // [8192][64] bf16, row side
        const __hip_bfloat16* __restrict__ matB,   // [8192][64] bf16, col side
        const float* __restrict__ bias_in,         // [8192] log2-domain col bias
        const float* __restrict__ sq_row,          // [8192]
        const float* __restrict__ lw2_row,         // [8192]
        float* __restrict__ pot_out,               // [8192]
        float* __restrict__ bias_out) {            // [8192]
    __shared__ float2 comb[32 * 16];

    const int tid  = threadIdx.x;
    const int w    = tid >> 6;        // wave 0..15
    const int lane = tid & 63;
    const int quad = lane >> 4;       // k-group
    const int ln   = lane & 15;       // row (A) / col (B) within tile
    const int rb   = blockIdx.x * 32;

    const short8* A8 = (const short8*)matA;
    const short8* B8 = (const short8*)matB;

    // A fragments for 2 row-tiles (resident all pass). Lane holds row (ln),
    // k = quad*8 .. +8 ; second frag k+32.
    short8 a00 = A8[(rb + ln) * 8 + quad];
    short8 a01 = A8[(rb + ln) * 8 + quad + 4];
    short8 a10 = A8[(rb + 16 + ln) * 8 + quad];
    short8 a11 = A8[(rb + 16 + ln) * 8 + quad + 4];

    // per-lane online LSE state: 4 rows per row-tile (row = quad*4 + r)
    float m0[4], s0[4], m1[4], s1[4];
    #pragma unroll
    for (int r = 0; r < 4; r++) { m0[r] = -1e30f; s0[r] = 0.f; m1[r] = -1e30f; s1[r] = 0.f; }

    const int col_base = w * 512;
    const short8* bp  = B8 + (col_base + ln) * 8 + quad;
    const float*  bip = bias_in + col_base + ln;

    short8 b0 = bp[0];
    short8 b1 = bp[4];
    float  cb = *bip;

    for (int jt = 0; jt < 32; jt++) {
        float4v acc0 = {0.f, 0.f, 0.f, 0.f};
        float4v acc1 = {0.f, 0.f, 0.f, 0.f};
        acc0 = __builtin_amdgcn_mfma_f32_16x16x32_bf16(a00, b0, acc0, 0, 0, 0);
        acc0 = __builtin_amdgcn_mfma_f32_16x16x32_bf16(a01, b1, acc0, 0, 0, 0);
        acc1 = __builtin_amdgcn_mfma_f32_16x16x32_bf16(a10, b0, acc1, 0, 0, 0);
        acc1 = __builtin_amdgcn_mfma_f32_16x16x32_bf16(a11, b1, acc1, 0, 0, 0);

        // prefetch next tile NOW (over-reads at most 2 KB past matB into
        // adjacent workspace — safe, values unused on last iter)
        bp += 128; bip += 16;
        short8 nb0 = bp[0];
        short8 nb1 = bp[4];
        float  ncb = *bip;

        // online LSE update; exactly one of {z-m', m-m'} is 0, so one exp2:
        //   e = exp2(-|z-m|); z>m: s = s*e + 1 ; else: s = s + e
        #pragma unroll
        for (int r = 0; r < 4; r++) {
            float z = fmaf(S2, acc0[r], cb);
            float t = z - m0[r];
            float e = __builtin_amdgcn_exp2f(-fabsf(t));
            bool  g = z > m0[r];
            m0[r] = fmaxf(m0[r], z);
            s0[r] = fmaf(s0[r], g ? e : 1.0f, g ? 1.0f : e);
        }
        #pragma unroll
        for (int r = 0; r < 4; r++) {
            float z = fmaf(S2, acc1[r], cb);
            float t = z - m1[r];
            float e = __builtin_amdgcn_exp2f(-fabsf(t));
            bool  g = z > m1[r];
            m1[r] = fmaxf(m1[r], z);
            s1[r] = fmaf(s1[r], g ? e : 1.0f, g ? 1.0f : e);
        }

        b0 = nb0; b1 = nb1; cb = ncb;
    }

    // combine across the 16 lanes sharing the same rows (same quad group)
    #pragma unroll
    for (int mask = 1; mask < 16; mask <<= 1) {
        #pragma unroll
        for (int r = 0; r < 4; r++) {
            float mo = __shfl_xor(m0[r], mask, 64);
            float so = __shfl_xor(s0[r], mask, 64);
            float M  = fmaxf(m0[r], mo);
            s0[r] = s0[r] * __builtin_amdgcn_exp2f(m0[r] - M)
                  + so    * __builtin_amdgcn_exp2f(mo    - M);
            m0[r] = M;
            mo = __shfl_xor(m1[r], mask, 64);
            so = __shfl_xor(s1[r], mask, 64);
            M  = fmaxf(m1[r], mo);
            s1[r] = s1[r] * __builtin_amdgcn_exp2f(m1[r] - M)
                  + so    * __builtin_amdgcn_exp2f(mo    - M);
            m1[r] = M;
        }
    }

    if (ln == 0) {   // lanes 0,16,32,48 hold the per-wave result
        #pragma unroll
        for (int r = 0; r < 4; r++) {
            comb[(quad * 4 + r) * 16 + w]      = make_float2(m0[r], s0[r]);
            comb[(16 + quad * 4 + r) * 16 + w] = make_float2(m1[r], s1[r]);
        }
    }
    __syncthreads();

    // combine across 16 waves (column partitions) and write outputs
    if (tid < 32) {
        float M = -1e30f;
        #pragma unroll
        for (int ww = 0; ww < 16; ww++) M = fmaxf(M, comb[tid * 16 + ww].x);
        float S = 0.f;
        #pragma unroll
        for (int ww = 0; ww < 16; ww++) {
            float2 c = comb[tid * 16 + ww];
            S += c.y * __builtin_amdgcn_exp2f(c.x - M);
        }
        float L = M + __builtin_amdgcn_logf(S);   // log2-domain LSE
        int row = rb + tid;
        pot_out[row]  = sq_row[row] - EPSLN2 * L;
        bias_out[row] = lw2_row[row] - L;
    }
}

// ---- final reduction: <a,f_fin>/sum_a + <b,g_fin>/sum_b --------------------
__global__ void reduce_kernel(const float* __restrict__ a, const float* __restrict__ b,
                              const float* __restrict__ sums,
                              const float* __restrict__ ffin, const float* __restrict__ gfin,
                              float* __restrict__ out) {
    __shared__ float red[32];
    int tid = threadIdx.x;
    float da = 0.f, db = 0.f;
    for (int i = tid; i < NR; i += blockDim.x) { da += a[i] * ffin[i]; db += b[i] * gfin[i]; }
    da = wave_reduce_sum(da);
    db = wave_reduce_sum(db);
    int wid = tid >> 6, ln = tid & 63;
    if (ln == 0) { red[wid] = da; red[wid + 16] = db; }
    __syncthreads();
    if (tid == 0) {
        float DA = 0.f, DB = 0.f;
        int nw = blockDim.x >> 6;
        for (int w = 0; w < nw; w++) { DA += red[w]; DB += red[w + 16]; }
        out[0] = DA / sums[2] + DB / sums[3];
    }
}

extern "C" void kernel_launch(void* const* d_in, const int* in_sizes, int n_in,
                              void* d_out, int out_size, void* d_ws, size_t ws_size,
                              hipStream_t stream) {
    const float* a = (const float*)d_in[0];
    const float* x = (const float*)d_in[1];
    const float* b = (const float*)d_in[2];
    const float* y = (const float*)d_in[3];

    char* ws = (char*)d_ws;
    __hip_bfloat16* xb = (__hip_bfloat16*)ws;                      // 1 MB
    __hip_bfloat16* yb = (__hip_bfloat16*)(ws + (1 << 20));        // 1 MB
    float* fp       = (float*)(ws + (2 << 20));
    float* x2       = fp + 0 * NR;
    float* y2       = fp + 1 * NR;
    float* la2      = fp + 2 * NR;
    float* lb2      = fp + 3 * NR;
    float* bias_c   = fp + 4 * NR;
    float* bias_r   = fp + 5 * NR;
    float* bias_jnk = fp + 6 * NR;
    float* f        = fp + 7 * NR;
    float* g        = fp + 8 * NR;
    float* f_fin    = fp + 9 * NR;
    float* g_fin    = fp + 10 * NR;
    float* sums     = fp + 11 * NR;

    sums_kernel<<<1, 1024, 0, stream>>>(a, b, sums);
    prep_kernel<<<(2 * NR) / 4, 256, 0, stream>>>(x, y, a, b, sums,
                                                  xb, yb, x2, y2, la2, lb2, bias_c);

    for (int it = 0; it < N_ITERS; it++) {
        // f = softmin_rows(g): uses bias_c (from g), emits bias_r (from new f)
        pass_kernel<<<256, 1024, 0, stream>>>(xb, yb, bias_c, x2, la2, f, bias_r);
        // g = softmin_cols(f): uses bias_r, emits bias_c
        pass_kernel<<<256, 1024, 0, stream>>>(yb, xb, bias_r, y2, lb2, g, bias_c);
    }
    // final symmetric update from detached potentials:
    // f_fin from g20 (bias_c), g_fin from f20 (bias_r — must not be clobbered)
    pass_kernel<<<256, 1024, 0, stream>>>(xb, yb, bias_c, x2, la2, f_fin, bias_jnk);
    pass_kernel<<<256, 1024, 0, stream>>>(yb, xb, bias_r, y2, lb2, g_fin, bias_jnk);

    reduce_kernel<<<1, 1024, 0, stream>>>(a, b, sums, f_fin, g_fin, (float*)d_out);
}

// Round 3
// 1554.451 us; speedup vs baseline: 1.0045x; 1.0045x over previous
//
#include <hip/hip_runtime.h>
#include <hip/hip_bf16.h>

#define EPS       0.05f
#define N_ITERS   20
#define NR        8192      // N == M
#define DIM       64
#define LOG2E     1.4426950408889634f
#define LN2       0.6931471805599453f
#define S2        (2.0f * LOG2E / EPS)   // 57.7078...
#define EPSLN2    (EPS * LN2)

typedef __attribute__((ext_vector_type(8))) short short8;
typedef __attribute__((ext_vector_type(4))) float float4v;

__device__ __forceinline__ float wave_reduce_sum(float v) {
    #pragma unroll
    for (int m = 1; m < 64; m <<= 1) v += __shfl_xor(v, m, 64);
    return v;
}

// ---- setup: sums of a and b ------------------------------------------------
__global__ void sums_kernel(const float* __restrict__ a, const float* __restrict__ b,
                            float* __restrict__ sums) {
    __shared__ float red[32];
    int tid = threadIdx.x;
    float pa = 0.f, pb = 0.f;
    for (int i = tid; i < NR; i += blockDim.x) { pa += a[i]; pb += b[i]; }
    pa = wave_reduce_sum(pa);
    pb = wave_reduce_sum(pb);
    int wid = tid >> 6, ln = tid & 63;
    if (ln == 0) { red[wid] = pa; red[wid + 16] = pb; }
    __syncthreads();
    if (tid == 0) {
        float sa = 0.f, sb = 0.f;
        int nw = blockDim.x >> 6;
        for (int w = 0; w < nw; w++) { sa += red[w]; sb += red[w + 16]; }
        sums[0] = logf(sa); sums[1] = logf(sb); sums[2] = sa; sums[3] = sb;
    }
}

// ---- setup: bf16 copies, squared norms, log-weights, initial col bias ------
__global__ void prep_kernel(const float* __restrict__ x, const float* __restrict__ y,
                            const float* __restrict__ a, const float* __restrict__ b,
                            const float* __restrict__ sums,
                            __hip_bfloat16* __restrict__ xb, __hip_bfloat16* __restrict__ yb,
                            float* __restrict__ x2, float* __restrict__ y2,
                            float* __restrict__ la2, float* __restrict__ lb2,
                            float* __restrict__ bias_c) {
    int gw = blockIdx.x * (blockDim.x >> 6) + (threadIdx.x >> 6);
    int ln = threadIdx.x & 63;
    bool isx = gw < NR;
    int row = isx ? gw : gw - NR;
    const float* src = isx ? x : y;
    float v = src[row * DIM + ln];
    float sq = wave_reduce_sum(v * v);
    (isx ? xb : yb)[row * DIM + ln] = __float2bfloat16(v);
    if (ln == 0) {
        if (isx) {
            x2[row] = sq;
            la2[row] = (logf(a[row]) - sums[0]) * LOG2E;
        } else {
            y2[row] = sq;
            float lw = (logf(b[row]) - sums[1]) * LOG2E;
            lb2[row] = lw;
            bias_c[row] = lw - sq * (LOG2E / EPS);   // g = 0 initially
        }
    }
}

#define LSE_UPDATE(acc, cbv, mm, ss)                                  \
    {                                                                 \
        float z = fmaf(S2, (acc), (cbv));                             \
        float t = z - (mm);                                           \
        float e = __builtin_amdgcn_exp2f(-fabsf(t));                  \
        bool  gg = z > (mm);                                          \
        (mm) = fmaxf((mm), z);                                        \
        (ss) = fmaf((ss), gg ? e : 1.0f, gg ? 1.0f : e);              \
    }

// ---- one softmin sweep -----------------------------------------------------
// out_i = sq_row_i - eps*ln2 * LSE2_j( bias_in_j + S2 * <A_i, B_j> )
// bias_out_i = lw2_row_i - LSE2_i
// Block: 1024 thr = 16 waves; block covers 32 rows, each wave 512 cols.
// R3: MFMA software pipeline across the loop boundary — epilogue of tile
// jt-1 runs between MFMA issue and acc consumption of tile jt, so the
// matrix-pipe latency hides under ~176 cyc of independent VALU work.
__global__ __launch_bounds__(1024, 4) void pass_kernel(
        const __hip_bfloat16* __restrict__ matA,   // [8192][64] bf16, row side
        const __hip_bfloat16* __restrict__ matB,   // [8192][64] bf16, col side
        const float* __restrict__ bias_in,         // [8192] log2-domain col bias
        const float* __restrict__ sq_row,          // [8192]
        const float* __restrict__ lw2_row,         // [8192]
        float* __restrict__ pot_out,               // [8192]
        float* __restrict__ bias_out) {            // [8192]
    __shared__ float2 comb[32 * 16];

    const int tid  = threadIdx.x;
    const int w    = tid >> 6;        // wave 0..15
    const int lane = tid & 63;
    const int quad = lane >> 4;       // k-group
    const int ln   = lane & 15;       // row (A) / col (B) within tile
    const int rb   = blockIdx.x * 32;

    const short8* A8 = (const short8*)matA;
    const short8* B8 = (const short8*)matB;

    short8 a00 = A8[(rb + ln) * 8 + quad];
    short8 a01 = A8[(rb + ln) * 8 + quad + 4];
    short8 a10 = A8[(rb + 16 + ln) * 8 + quad];
    short8 a11 = A8[(rb + 16 + ln) * 8 + quad + 4];

    float m0[4], s0[4], m1[4], s1[4];
    #pragma unroll
    for (int r = 0; r < 4; r++) { m0[r] = -1e30f; s0[r] = 0.f; m1[r] = -1e30f; s1[r] = 0.f; }

    const int col_base = w * 512;
    const short8* bp  = B8 + (col_base + ln) * 8 + quad;
    const float*  bip = bias_in + col_base + ln;

    // ---- pipeline prologue: tile 0 loaded, MFMA'd into acc_prev ----
    short8 bc0 = bp[0];
    short8 bc1 = bp[4];
    float  cbc = *bip;
    bp += 128; bip += 16;

    float4v pa0 = {0.f, 0.f, 0.f, 0.f};
    float4v pa1 = {0.f, 0.f, 0.f, 0.f};
    pa0 = __builtin_amdgcn_mfma_f32_16x16x32_bf16(a00, bc0, pa0, 0, 0, 0);
    pa0 = __builtin_amdgcn_mfma_f32_16x16x32_bf16(a01, bc1, pa0, 0, 0, 0);
    pa1 = __builtin_amdgcn_mfma_f32_16x16x32_bf16(a10, bc0, pa1, 0, 0, 0);
    pa1 = __builtin_amdgcn_mfma_f32_16x16x32_bf16(a11, bc1, pa1, 0, 0, 0);
    float cbp = cbc;

    // tile 1 frags
    bc0 = bp[0];
    bc1 = bp[4];
    cbc = *bip;

    for (int jt = 1; jt < 32; jt++) {
        bp += 128; bip += 16;

        // MFMAs for current tile jt (results consumed NEXT iteration)
        float4v ca0 = {0.f, 0.f, 0.f, 0.f};
        float4v ca1 = {0.f, 0.f, 0.f, 0.f};
        ca0 = __builtin_amdgcn_mfma_f32_16x16x32_bf16(a00, bc0, ca0, 0, 0, 0);
        ca0 = __builtin_amdgcn_mfma_f32_16x16x32_bf16(a01, bc1, ca0, 0, 0, 0);
        ca1 = __builtin_amdgcn_mfma_f32_16x16x32_bf16(a10, bc0, ca1, 0, 0, 0);
        ca1 = __builtin_amdgcn_mfma_f32_16x16x32_bf16(a11, bc1, ca1, 0, 0, 0);
        float cb_cur = cbc;

        // prefetch tile jt+1 (bounded overread into adjacent ws arrays on
        // the last iteration — values unused, memory valid)
        short8 nb0 = bp[0];
        short8 nb1 = bp[4];
        float  ncb = *bip;

        // epilogue on tile jt-1 (pa0/pa1, cbp) — independent of the MFMAs above
        #pragma unroll
        for (int r = 0; r < 4; r++) LSE_UPDATE(pa0[r], cbp, m0[r], s0[r]);
        #pragma unroll
        for (int r = 0; r < 4; r++) LSE_UPDATE(pa1[r], cbp, m1[r], s1[r]);

        // rotate pipeline registers
        pa0 = ca0; pa1 = ca1; cbp = cb_cur;
        bc0 = nb0; bc1 = nb1; cbc = ncb;
    }

    // drain: epilogue on the last tile
    #pragma unroll
    for (int r = 0; r < 4; r++) LSE_UPDATE(pa0[r], cbp, m0[r], s0[r]);
    #pragma unroll
    for (int r = 0; r < 4; r++) LSE_UPDATE(pa1[r], cbp, m1[r], s1[r]);

    // combine across the 16 lanes sharing the same rows (same quad group)
    #pragma unroll
    for (int mask = 1; mask < 16; mask <<= 1) {
        #pragma unroll
        for (int r = 0; r < 4; r++) {
            float mo = __shfl_xor(m0[r], mask, 64);
            float so = __shfl_xor(s0[r], mask, 64);
            float M  = fmaxf(m0[r], mo);
            s0[r] = s0[r] * __builtin_amdgcn_exp2f(m0[r] - M)
                  + so    * __builtin_amdgcn_exp2f(mo    - M);
            m0[r] = M;
            mo = __shfl_xor(m1[r], mask, 64);
            so = __shfl_xor(s1[r], mask, 64);
            M  = fmaxf(m1[r], mo);
            s1[r] = s1[r] * __builtin_amdgcn_exp2f(m1[r] - M)
                  + so    * __builtin_amdgcn_exp2f(mo    - M);
            m1[r] = M;
        }
    }

    if (ln == 0) {   // lanes 0,16,32,48 hold the per-wave result
        #pragma unroll
        for (int r = 0; r < 4; r++) {
            comb[(quad * 4 + r) * 16 + w]      = make_float2(m0[r], s0[r]);
            comb[(16 + quad * 4 + r) * 16 + w] = make_float2(m1[r], s1[r]);
        }
    }
    __syncthreads();

    // combine across 16 waves (column partitions) and write outputs
    if (tid < 32) {
        float M = -1e30f;
        #pragma unroll
        for (int ww = 0; ww < 16; ww++) M = fmaxf(M, comb[tid * 16 + ww].x);
        float S = 0.f;
        #pragma unroll
        for (int ww = 0; ww < 16; ww++) {
            float2 c = comb[tid * 16 + ww];
            S += c.y * __builtin_amdgcn_exp2f(c.x - M);
        }
        float L = M + __builtin_amdgcn_logf(S);   // log2-domain LSE
        int row = rb + tid;
        pot_out[row]  = sq_row[row] - EPSLN2 * L;
        bias_out[row] = lw2_row[row] - L;
    }
}

// ---- final reduction: <a,f_fin>/sum_a + <b,g_fin>/sum_b --------------------
__global__ void reduce_kernel(const float* __restrict__ a, const float* __restrict__ b,
                              const float* __restrict__ sums,
                              const float* __restrict__ ffin, const float* __restrict__ gfin,
                              float* __restrict__ out) {
    __shared__ float red[32];
    int tid = threadIdx.x;
    float da = 0.f, db = 0.f;
    for (int i = tid; i < NR; i += blockDim.x) { da += a[i] * ffin[i]; db += b[i] * gfin[i]; }
    da = wave_reduce_sum(da);
    db = wave_reduce_sum(db);
    int wid = tid >> 6, ln = tid & 63;
    if (ln == 0) { red[wid] = da; red[wid + 16] = db; }
    __syncthreads();
    if (tid == 0) {
        float DA = 0.f, DB = 0.f;
        int nw = blockDim.x >> 6;
        for (int w = 0; w < nw; w++) { DA += red[w]; DB += red[w + 16]; }
        out[0] = DA / sums[2] + DB / sums[3];
    }
}

extern "C" void kernel_launch(void* const* d_in, const int* in_sizes, int n_in,
                              void* d_out, int out_size, void* d_ws, size_t ws_size,
                              hipStream_t stream) {
    const float* a = (const float*)d_in[0];
    const float* x = (const float*)d_in[1];
    const float* b = (const float*)d_in[2];
    const float* y = (const float*)d_in[3];

    char* ws = (char*)d_ws;
    __hip_bfloat16* xb = (__hip_bfloat16*)ws;                      // 1 MB
    __hip_bfloat16* yb = (__hip_bfloat16*)(ws + (1 << 20));        // 1 MB
    float* fp       = (float*)(ws + (2 << 20));
    float* x2       = fp + 0 * NR;
    float* y2       = fp + 1 * NR;
    float* la2      = fp + 2 * NR;
    float* lb2      = fp + 3 * NR;
    float* bias_c   = fp + 4 * NR;
    float* bias_r   = fp + 5 * NR;
    float* bias_jnk = fp + 6 * NR;
    float* f        = fp + 7 * NR;
    float* g        = fp + 8 * NR;
    float* f_fin    = fp + 9 * NR;
    float* g_fin    = fp + 10 * NR;
    float* sums     = fp + 11 * NR;

    sums_kernel<<<1, 1024, 0, stream>>>(a, b, sums);
    prep_kernel<<<(2 * NR) / 4, 256, 0, stream>>>(x, y, a, b, sums,
                                                  xb, yb, x2, y2, la2, lb2, bias_c);

    for (int it = 0; it < N_ITERS; it++) {
        // f = softmin_rows(g): uses bias_c (from g), emits bias_r (from new f)
        pass_kernel<<<256, 1024, 0, stream>>>(xb, yb, bias_c, x2, la2, f, bias_r);
        // g = softmin_cols(f): uses bias_r, emits bias_c
        pass_kernel<<<256, 1024, 0, stream>>>(yb, xb, bias_r, y2, lb2, g, bias_c);
    }
    // final symmetric update from detached potentials:
    // f_fin from g20 (bias_c), g_fin from f20 (bias_r — must not be clobbered)
    pass_kernel<<<256, 1024, 0, stream>>>(xb, yb, bias_c, x2, la2, f_fin, bias_jnk);
    pass_kernel<<<256, 1024, 0, stream>>>(yb, xb, bias_r, y2, lb2, g_fin, bias_jnk);

    reduce_kernel<<<1, 1024, 0, stream>>>(a, b, sums, f_fin, g_fin, (float*)d_out);
}